// Round 7
// baseline (347.852 us; speedup 1.0000x reference)
//
#include <hip/hip_runtime.h>

// ============================================================================
// MolecularGraphNeuralNetwork — fused, one workgroup per molecule.
// ROUND 7 = ROUND 6 (R4 + adjacency bitmask) + TBAA de-aliasing:
//   * every vector LDS access goes through __builtin_memcpy (may-alias) —
//     the compiler can no longer sink ds_read_b128 past the scalar short
//     stores that overwrite the same strip (suspected root cause of ALL
//     schedule-dependent failures: h1f/xsf loads sunk past STAGE_STRIP).
//   * adjbits read as properly-typed u64 >> lane (no u32* cast).
//   * zero-cost compiler fences after each READ_AFRAG (belt-and-braces).
// ============================================================================

#define NB   1024
#define NN   256
#define DD   64
#define NLAY 3

typedef __attribute__((ext_vector_type(8))) short s16x8;
typedef __attribute__((ext_vector_type(4))) short s16x4;
typedef __attribute__((ext_vector_type(4))) float f32x4;

static __device__ __forceinline__ short f2bf(float x) {
    union { float f; unsigned u; } v; v.f = x;
    unsigned r = v.u + 0x7FFFu + ((v.u >> 16) & 1u);   // RNE
    return (short)(r >> 16);
}

// may-alias LDS accessors: same ds_read_b128/ds_write_b64 codegen, but the
// compiler must preserve program order vs ANY potentially-aliasing store.
static __device__ __forceinline__ s16x8 lds_read8(const short* p) {
    s16x8 v; __builtin_memcpy(&v, p, 16); return v;
}
static __device__ __forceinline__ void lds_write4(short* p, s16x4 v) {
    __builtin_memcpy(p, &v, 8);
}

#define MFMA(a, bb, acc) __builtin_amdgcn_mfma_f32_16x16x32_bf16((a), (bb), (acc), 0, 0, 0)

// stage gemm output hsv (acc layout: row 4g+r, col 16et+c) into wave strip
// (scalar short stores — correct TBAA type for hs2s)
#define STAGE_STRIP(arr)                                                      \
    do {                                                                      \
        _Pragma("unroll") for (int tr_ = 0; tr_ < 2; ++tr_)                   \
        _Pragma("unroll") for (int et_ = 0; et_ < 4; ++et_)                   \
        _Pragma("unroll") for (int r_ = 0; r_ < 4; ++r_)                      \
            hs2s[n0 + tr_*16 + g*4 + r_][et_*16 + c] = f2bf(arr[tr_][et_][r_]); \
    } while (0)

// read this wave's strip back as MFMA A/B fragments [tr][kblock]
#define READ_AFRAG(dst)                                                       \
    do {                                                                      \
        _Pragma("unroll") for (int tr_ = 0; tr_ < 2; ++tr_)                   \
        _Pragma("unroll") for (int kb_ = 0; kb_ < 2; ++kb_)                   \
            dst[tr_][kb_] = lds_read8(&hs2s[n0 + tr_*16 + c][kb_*32 + g*8]);  \
    } while (0)

// transposed adjacency loads (adj symmetric): am[tr][mc][r] = adj[m][n]
//   m = cc*32 + mc*16 + g*4 + r,  n = n0 + tr*16 + c
#define LOADA(cc, am)                                                         \
    do {                                                                      \
        _Pragma("unroll") for (int tr_ = 0; tr_ < 2; ++tr_)                   \
        _Pragma("unroll") for (int mc_ = 0; mc_ < 2; ++mc_)                   \
        _Pragma("unroll") for (int r_ = 0; r_ < 4; ++r_)                      \
            am[tr_][mc_][r_] = adjB[(size_t)((cc)*32 + mc_*16 + g*4 + r_)*NN + n0 + tr_*16 + c]; \
    } while (0)

// ballot-pack one chunk's mask: bit `lane` of word (tr*2+mc)*4+r  =  its (m,n)
#define PACKB(cc, am)                                                         \
    do {                                                                      \
        unsigned long long bbuf_[16];                                         \
        _Pragma("unroll") for (int tr_ = 0; tr_ < 2; ++tr_)                   \
        _Pragma("unroll") for (int mc_ = 0; mc_ < 2; ++mc_)                   \
        _Pragma("unroll") for (int r_ = 0; r_ < 4; ++r_)                      \
            bbuf_[(tr_*2 + mc_)*4 + r_] = __ballot(am[tr_][mc_][r_] != 0.f);  \
        if (lane == 0) {                                                      \
            _Pragma("unroll") for (int i_ = 0; i_ < 16; ++i_)                 \
                adjbits[w][cc][i_] = bbuf_[i_];                               \
        }                                                                     \
    } while (0)

__global__ __launch_bounds__(512, 2)
void mgnn_fused(const int* __restrict__ fpr, const float* __restrict__ adj,
                const float* __restrict__ wemb, const float* __restrict__ pemb,
                const float* __restrict__ egp, const float* __restrict__ ebp,
                const float* __restrict__ W1p, const float* __restrict__ b1p,
                const float* __restrict__ W2p, const float* __restrict__ b2p,
                const float* __restrict__ W3p, const float* __restrict__ b3p,
                const float* __restrict__ lngp, const float* __restrict__ lnbp,
                float* __restrict__ out)
{
    // LDS: 36,864 + 33,792 + 8,192 = 78,848 B
    __shared__ __align__(16) short hs2s[NN][72];    // bf16 staging (xs/hs1/hs2)
    __shared__ __align__(16) short hs3Ts[DD][264];  // hs3^T bf16 [d][m], +8 pad
    __shared__ unsigned long long adjbits[8][8][16]; // [wave][chunk][word]

    const int b    = blockIdx.x;
    const int tid  = threadIdx.x;
    const int w    = tid >> 6;      // wave 0..7
    const int lane = tid & 63;
    const int g    = lane >> 4;     // lane group 0..3
    const int c    = lane & 15;     // lane-in-group 0..15
    const int n0   = w * 32;        // this wave's row strip

    const float* __restrict__ adjB = adj + (size_t)b * NN * NN;

    // ---- embedding + LN, TRANSPOSED layout:
    //      lane (g,c), tile tr holds row n = n0+16tr+c, cols d = 16dc+4g+r
    f32x4 xsC[2][4];
    #pragma unroll
    for (int tr = 0; tr < 2; ++tr) {
        const int n = n0 + tr*16 + c;
        const int f = fpr[b*NN + n];
        f32x4 v[4];
        float s1 = 0.f, s2 = 0.f;
        #pragma unroll
        for (int dc = 0; dc < 4; ++dc) {
            const f32x4 wv = *(const f32x4*)&wemb[f*DD + dc*16 + g*4];
            const f32x4 pe = *(const f32x4*)&pemb[n*DD + dc*16 + g*4];
            f32x4 t;
            #pragma unroll
            for (int r = 0; r < 4; ++r) {
                t[r] = wv[r] + pe[r]; s1 += t[r]; s2 += t[r]*t[r];
            }
            v[dc] = t;
        }
        s1 += __shfl_xor(s1, 16); s2 += __shfl_xor(s2, 16);
        s1 += __shfl_xor(s1, 32); s2 += __shfl_xor(s2, 32);
        const float mu  = s1 * 0.015625f;
        const float var = s2 * 0.015625f - mu*mu;
        const float rs  = rsqrtf(var + 1e-6f);
        #pragma unroll
        for (int dc = 0; dc < 4; ++dc) {
            const f32x4 eg = *(const f32x4*)&egp[dc*16 + g*4];
            const f32x4 eb = *(const f32x4*)&ebp[dc*16 + g*4];
            #pragma unroll
            for (int r = 0; r < 4; ++r)
                xsC[tr][dc][r] = (v[dc][r] - mu) * rs * eg[r] + eb[r];
        }
    }

    // stage xs (transposed regs -> row-major LDS strip): may-alias s16x4 stores
    auto stageXS = [&]() {
        #pragma unroll
        for (int tr = 0; tr < 2; ++tr)
            #pragma unroll
            for (int dc = 0; dc < 4; ++dc) {
                s16x4 pk;
                #pragma unroll
                for (int r = 0; r < 4; ++r) pk[r] = f2bf(xsC[tr][dc][r]);
                lds_write4(&hs2s[n0 + tr*16 + c][dc*16 + g*4], pk);
            }
    };

    s16x8 xsf[2][2];
    stageXS();
    __syncthreads();
    READ_AFRAG(xsf);
    asm volatile("" ::: "memory");   // xsf reads stay above later strip writes

    // ---- pack adjacency bits (double-buffered global loads), once ---------
    {
        float amA[2][2][4], amB[2][2][4];
        LOADA(0, amA);
        #pragma unroll 1
        for (int cc = 0; cc < 8; cc += 2) {
            LOADA(cc + 1, amB);
            PACKB(cc, amA);
            if (cc + 2 < 8) LOADA(cc + 2, amA);
            PACKB(cc + 1, amB);
        }
    }

    float hsv[2][4][4];   // gemm output, acc layout [tr][et][r]

    // hsv = relu(xs @ W^T + bias); W is [e][d] row-major f32
    auto gemmHs = [&](const float* __restrict__ Wm, const float* __restrict__ bm) {
        s16x8 wf[4][2];
        #pragma unroll
        for (int et = 0; et < 4; ++et) {
            const float* p = Wm + (et*16 + c)*DD + g*8;
            #pragma unroll
            for (int kb = 0; kb < 2; ++kb) {
                s16x8 v;
                #pragma unroll
                for (int j = 0; j < 8; ++j) v[j] = f2bf(p[kb*32 + j]);
                wf[et][kb] = v;
            }
        }
        #pragma unroll
        for (int tr = 0; tr < 2; ++tr) {
            #pragma unroll
            for (int et = 0; et < 4; ++et) {
                f32x4 acc = {0.f, 0.f, 0.f, 0.f};
                acc = MFMA(xsf[tr][0], wf[et][0], acc);
                acc = MFMA(xsf[tr][1], wf[et][1], acc);
                const float bv = bm[et*16 + c];
                #pragma unroll
                for (int r = 0; r < 4; ++r)
                    hsv[tr][et][r] = fmaxf(acc[r] + bv, 0.f);
            }
        }
    };

    #pragma unroll 1
    for (int l = 0; l < NLAY; ++l) {
        // ---- hs1 -> strip -> A/B-frags
        gemmHs(W1p + l*DD*DD, b1p + l*DD);
        STAGE_STRIP(hsv);
        __syncthreads();
        s16x8 h1f[2][2];
        READ_AFRAG(h1f);
        asm volatile("" ::: "memory");   // h1f reads stay above hs2 strip writes

        // ---- hs2 -> strip (row-major, read by all waves in chunk loop)
        gemmHs(W2p + l*DD*DD, b2p + l*DD);
        STAGE_STRIP(hsv);

        // ---- hs3 -> LDS transposed [d][m], bf16
        gemmHs(W3p + l*DD*DD, b3p + l*DD);
        #pragma unroll
        for (int tr = 0; tr < 2; ++tr) {
            #pragma unroll
            for (int et = 0; et < 4; ++et) {
                s16x4 pk;
                #pragma unroll
                for (int r = 0; r < 4; ++r) pk[r] = f2bf(hsv[tr][et][r]);
                lds_write4(&hs3Ts[et*16 + c][n0 + tr*16 + g*4], pk);
            }
        }
        __syncthreads();   // hs2 strips + hs3T visible to all waves

        // ---- masked attention + PV, 8 chunks of 32 m-columns --------------
        // pv transposed: lane (g,c) tile (tr,dc): PV[n=n0+16tr+c][d=16dc+4g+r]
        f32x4 pv[2][4];
        {
            const f32x4 z4 = {0.f, 0.f, 0.f, 0.f};
            #pragma unroll
            for (int tr = 0; tr < 2; ++tr)
                #pragma unroll
                for (int dc = 0; dc < 4; ++dc) pv[tr][dc] = z4;
        }

        #pragma unroll 1
        for (int cc = 0; cc < 8; ++cc) {
            // hs2 chunk-row fragments (A-slot of S^T)
            s16x8 a2[2][2];
            #pragma unroll
            for (int mc = 0; mc < 2; ++mc)
                #pragma unroll
                for (int kb = 0; kb < 2; ++kb)
                    a2[mc][kb] = lds_read8(&hs2s[cc*32 + mc*16 + c][kb*32 + g*8]);

            // hs3^T fragments (A-slot of PV)
            s16x8 h3f[4];
            #pragma unroll
            for (int dc = 0; dc < 4; ++dc)
                h3f[dc] = lds_read8(&hs3Ts[dc*16 + c][cc*32 + g*8]);

            // S^T tiles: reg r of lane (g,c) = S^T[m=16mc+4g+r][n=16tr+c],
            // masked via adjacency bit (bit-select == multiply by {0,1})
            float smv[2][2][4];
            #pragma unroll
            for (int tr = 0; tr < 2; ++tr) {
                #pragma unroll
                for (int mc = 0; mc < 2; ++mc) {
                    f32x4 st = {0.f, 0.f, 0.f, 0.f};
                    st = MFMA(a2[mc][0], h1f[tr][0], st);
                    st = MFMA(a2[mc][1], h1f[tr][1], st);
                    #pragma unroll
                    for (int r = 0; r < 4; ++r) {
                        const unsigned long long wv =
                            adjbits[w][cc][(tr*2 + mc)*4 + r];
                        smv[tr][mc][r] = ((wv >> lane) & 1ull) ? st[r] : 0.f;
                    }
                }
            }

            // build PV B-operand in registers + PV MFMAs
            // elem j of lane (g,c) = S'^T[m=8g+j][n-col c]
            //   = reg (j&3), tile (g>>1), of lane (2*(g&1)+(j>>2))*16 + c
            #pragma unroll
            for (int tr = 0; tr < 2; ++tr) {
                s16x8 pb;
                #pragma unroll
                for (int j = 0; j < 8; ++j) {
                    const int srcl = ((2*(g & 1) + (j >> 2)) << 4) | c;
                    const float v0 = __shfl(smv[tr][0][j & 3], srcl);
                    const float v1 = __shfl(smv[tr][1][j & 3], srcl);
                    pb[j] = f2bf((g & 2) ? v1 : v0);
                }
                #pragma unroll
                for (int dc = 0; dc < 4; ++dc)
                    pv[tr][dc] = MFMA(h3f[dc], pb, pv[tr][dc]);
            }
        }

        // ---- LayerNorm(pv) + residual (transposed layout) ------------------
        #pragma unroll
        for (int tr = 0; tr < 2; ++tr) {
            float s1 = 0.f, s2 = 0.f;
            #pragma unroll
            for (int dc = 0; dc < 4; ++dc)
                #pragma unroll
                for (int r = 0; r < 4; ++r) {
                    const float x = pv[tr][dc][r];
                    s1 += x; s2 += x*x;
                }
            s1 += __shfl_xor(s1, 16); s2 += __shfl_xor(s2, 16);
            s1 += __shfl_xor(s1, 32); s2 += __shfl_xor(s2, 32);
            const float mu  = s1 * 0.015625f;
            const float var = s2 * 0.015625f - mu*mu;
            const float rs  = rsqrtf(var + 1e-6f);
            #pragma unroll
            for (int dc = 0; dc < 4; ++dc) {
                const f32x4 lg = *(const f32x4*)&lngp[dc*16 + g*4];
                const f32x4 lb4 = *(const f32x4*)&lnbp[dc*16 + g*4];
                #pragma unroll
                for (int r = 0; r < 4; ++r)
                    xsC[tr][dc][r] += (pv[tr][dc][r] - mu) * rs * lg[r] + lb4[r];
            }
        }

        // ---- re-stage xs for next layer ------------------------------------
        if (l < NLAY - 1) {
            __syncthreads();          // all waves done reading hs2s/hs3Ts
            stageXS();
            __syncthreads();
            READ_AFRAG(xsf);
            asm volatile("" ::: "memory");
        }
    }

    // ---------------- final output: float4 per (tr,dc) ----------------------
    const size_t ob = (size_t)b * NN * DD;
    #pragma unroll
    for (int tr = 0; tr < 2; ++tr) {
        const int n = n0 + tr*16 + c;
        #pragma unroll
        for (int dc = 0; dc < 4; ++dc)
            *(f32x4*)&out[ob + (size_t)n*DD + dc*16 + g*4] = xsC[tr][dc];
    }
}

extern "C" void kernel_launch(void* const* d_in, const int* in_sizes, int n_in,
                              void* d_out, int out_size, void* d_ws, size_t ws_size,
                              hipStream_t stream) {
    const int*   fpr  = (const int*)  d_in[0];
    const float* adj  = (const float*)d_in[1];
    // d_in[2] = molecular_sizes — unused by the reference computation
    const float* wemb = (const float*)d_in[3];
    const float* pemb = (const float*)d_in[4];
    const float* eg   = (const float*)d_in[5];
    const float* eb   = (const float*)d_in[6];
    const float* W1   = (const float*)d_in[7];
    const float* b1   = (const float*)d_in[8];
    const float* W2   = (const float*)d_in[9];
    const float* b2   = (const float*)d_in[10];
    const float* W3   = (const float*)d_in[11];
    const float* b3   = (const float*)d_in[12];
    const float* lng  = (const float*)d_in[13];
    const float* lnb  = (const float*)d_in[14];

    mgnn_fused<<<dim3(NB), dim3(512), 0, stream>>>(
        fpr, adj, wemb, pemb, eg, eb, W1, b1, W2, b2, W3, b3, lng, lnb,
        (float*)d_out);
}

// Round 9
// 340.340 us; speedup vs baseline: 1.0221x; 1.0221x over previous
//
#include <hip/hip_runtime.h>

// ============================================================================
// MolecularGraphNeuralNetwork — fused, one workgroup per molecule.
// ROUND 9 = ROUND 7 (passing, 348us) + EXACTLY ONE change:
//   adjacency mask bits move from the 8KB LDS adjbits array into 2 u64 VGPRs
//   per lane, packed by DIRECT per-lane predicate (no __ballot, no cross-lane
//   op), rotated 16 bits per chunk.  Chunk loop masks via register bit test.
// Everything else (launch_bounds(512,2), scalar weight loads, per-element
// shuffle PV build, memcpy may-alias LDS accessors, fences) is byte-identical
// to Round 7.
// ============================================================================

#define NB   1024
#define NN   256
#define DD   64
#define NLAY 3

typedef __attribute__((ext_vector_type(8))) short s16x8;
typedef __attribute__((ext_vector_type(4))) short s16x4;
typedef __attribute__((ext_vector_type(4))) float f32x4;

static __device__ __forceinline__ short f2bf(float x) {
    union { float f; unsigned u; } v; v.f = x;
    unsigned r = v.u + 0x7FFFu + ((v.u >> 16) & 1u);   // RNE
    return (short)(r >> 16);
}

// may-alias LDS accessors (R7): compiler cannot reorder across aliasing stores
static __device__ __forceinline__ s16x8 lds_read8(const short* p) {
    s16x8 v; __builtin_memcpy(&v, p, 16); return v;
}
static __device__ __forceinline__ void lds_write4(short* p, s16x4 v) {
    __builtin_memcpy(p, &v, 8);
}

#define MFMA(a, bb, acc) __builtin_amdgcn_mfma_f32_16x16x32_bf16((a), (bb), (acc), 0, 0, 0)

// stage gemm output hsv (acc layout: row 4g+r, col 16et+c) into wave strip
#define STAGE_STRIP(arr)                                                      \
    do {                                                                      \
        _Pragma("unroll") for (int tr_ = 0; tr_ < 2; ++tr_)                   \
        _Pragma("unroll") for (int et_ = 0; et_ < 4; ++et_)                   \
        _Pragma("unroll") for (int r_ = 0; r_ < 4; ++r_)                      \
            hs2s[n0 + tr_*16 + g*4 + r_][et_*16 + c] = f2bf(arr[tr_][et_][r_]); \
    } while (0)

// read this wave's strip back as MFMA A/B fragments [tr][kblock]
#define READ_AFRAG(dst)                                                       \
    do {                                                                      \
        _Pragma("unroll") for (int tr_ = 0; tr_ < 2; ++tr_)                   \
        _Pragma("unroll") for (int kb_ = 0; kb_ < 2; ++kb_)                   \
            dst[tr_][kb_] = lds_read8(&hs2s[n0 + tr_*16 + c][kb_*32 + g*8]);  \
    } while (0)

// transposed adjacency loads (adj symmetric): am[tr][mc][r] = adj[m][n]
//   m = cc*32 + mc*16 + g*4 + r,  n = n0 + tr*16 + c
#define LOADA(cc, am)                                                         \
    do {                                                                      \
        _Pragma("unroll") for (int tr_ = 0; tr_ < 2; ++tr_)                   \
        _Pragma("unroll") for (int mc_ = 0; mc_ < 2; ++mc_)                   \
        _Pragma("unroll") for (int r_ = 0; r_ < 4; ++r_)                      \
            am[tr_][mc_][r_] = adjB[(size_t)((cc)*32 + mc_*16 + g*4 + r_)*NN + n0 + tr_*16 + c]; \
    } while (0)

// pack one chunk's mask into per-lane u64 registers, DIRECT predicate:
// bit ((cc)&3)*16 + (tr*2+mc)*4 + r of (cc<4 ? mA : mB) = (own am != 0).
#define PACKB(cc, am)                                                         \
    do {                                                                      \
        _Pragma("unroll") for (int tr_ = 0; tr_ < 2; ++tr_)                   \
        _Pragma("unroll") for (int mc_ = 0; mc_ < 2; ++mc_)                   \
        _Pragma("unroll") for (int r_ = 0; r_ < 4; ++r_) {                    \
            const unsigned long long bit_ =                                   \
                (unsigned long long)(am[tr_][mc_][r_] != 0.f);                \
            if ((cc) < 4) mA |= bit_ << (((cc)&3)*16 + (tr_*2 + mc_)*4 + r_); \
            else          mB |= bit_ << (((cc)&3)*16 + (tr_*2 + mc_)*4 + r_); \
        }                                                                     \
    } while (0)

__global__ __launch_bounds__(512, 2)
void mgnn_fused(const int* __restrict__ fpr, const float* __restrict__ adj,
                const float* __restrict__ wemb, const float* __restrict__ pemb,
                const float* __restrict__ egp, const float* __restrict__ ebp,
                const float* __restrict__ W1p, const float* __restrict__ b1p,
                const float* __restrict__ W2p, const float* __restrict__ b2p,
                const float* __restrict__ W3p, const float* __restrict__ b3p,
                const float* __restrict__ lngp, const float* __restrict__ lnbp,
                float* __restrict__ out)
{
    // LDS: 36,864 + 33,792 = 70,656 B
    __shared__ __align__(16) short hs2s[NN][72];    // bf16 staging (xs/hs1/hs2)
    __shared__ __align__(16) short hs3Ts[DD][264];  // hs3^T bf16 [d][m], +8 pad

    const int b    = blockIdx.x;
    const int tid  = threadIdx.x;
    const int w    = tid >> 6;      // wave 0..7
    const int lane = tid & 63;
    const int g    = lane >> 4;     // lane group 0..3
    const int c    = lane & 15;     // lane-in-group 0..15
    const int n0   = w * 32;        // this wave's row strip

    const float* __restrict__ adjB = adj + (size_t)b * NN * NN;

    // ---- embedding + LN, TRANSPOSED layout:
    //      lane (g,c), tile tr holds row n = n0+16tr+c, cols d = 16dc+4g+r
    f32x4 xsC[2][4];
    #pragma unroll
    for (int tr = 0; tr < 2; ++tr) {
        const int n = n0 + tr*16 + c;
        const int f = fpr[b*NN + n];
        f32x4 v[4];
        float s1 = 0.f, s2 = 0.f;
        #pragma unroll
        for (int dc = 0; dc < 4; ++dc) {
            const f32x4 wv = *(const f32x4*)&wemb[f*DD + dc*16 + g*4];
            const f32x4 pe = *(const f32x4*)&pemb[n*DD + dc*16 + g*4];
            f32x4 t;
            #pragma unroll
            for (int r = 0; r < 4; ++r) {
                t[r] = wv[r] + pe[r]; s1 += t[r]; s2 += t[r]*t[r];
            }
            v[dc] = t;
        }
        s1 += __shfl_xor(s1, 16); s2 += __shfl_xor(s2, 16);
        s1 += __shfl_xor(s1, 32); s2 += __shfl_xor(s2, 32);
        const float mu  = s1 * 0.015625f;
        const float var = s2 * 0.015625f - mu*mu;
        const float rs  = rsqrtf(var + 1e-6f);
        #pragma unroll
        for (int dc = 0; dc < 4; ++dc) {
            const f32x4 eg = *(const f32x4*)&egp[dc*16 + g*4];
            const f32x4 eb = *(const f32x4*)&ebp[dc*16 + g*4];
            #pragma unroll
            for (int r = 0; r < 4; ++r)
                xsC[tr][dc][r] = (v[dc][r] - mu) * rs * eg[r] + eb[r];
        }
    }

    // stage xs (transposed regs -> row-major LDS strip): may-alias s16x4 stores
    auto stageXS = [&]() {
        #pragma unroll
        for (int tr = 0; tr < 2; ++tr)
            #pragma unroll
            for (int dc = 0; dc < 4; ++dc) {
                s16x4 pk;
                #pragma unroll
                for (int r = 0; r < 4; ++r) pk[r] = f2bf(xsC[tr][dc][r]);
                lds_write4(&hs2s[n0 + tr*16 + c][dc*16 + g*4], pk);
            }
    };

    s16x8 xsf[2][2];
    stageXS();
    __syncthreads();
    READ_AFRAG(xsf);
    asm volatile("" ::: "memory");   // xsf reads stay above later strip writes

    // ---- pack adjacency bits into registers (double-buffered loads), once --
    unsigned long long mA = 0ull, mB = 0ull;
    {
        float amA[2][2][4], amB[2][2][4];
        LOADA(0, amA);
        #pragma unroll
        for (int cc = 0; cc < 8; cc += 2) {   // unrolled: cc is compile-time
            LOADA(cc + 1, amB);
            PACKB(cc, amA);
            if (cc + 2 < 8) LOADA(cc + 2, amA);
            PACKB(cc + 1, amB);
        }
    }

    float hsv[2][4][4];   // gemm output, acc layout [tr][et][r]

    // hsv = relu(xs @ W^T + bias); W is [e][d] row-major f32
    auto gemmHs = [&](const float* __restrict__ Wm, const float* __restrict__ bm) {
        s16x8 wf[4][2];
        #pragma unroll
        for (int et = 0; et < 4; ++et) {
            const float* p = Wm + (et*16 + c)*DD + g*8;
            #pragma unroll
            for (int kb = 0; kb < 2; ++kb) {
                s16x8 v;
                #pragma unroll
                for (int j = 0; j < 8; ++j) v[j] = f2bf(p[kb*32 + j]);
                wf[et][kb] = v;
            }
        }
        #pragma unroll
        for (int tr = 0; tr < 2; ++tr) {
            #pragma unroll
            for (int et = 0; et < 4; ++et) {
                f32x4 acc = {0.f, 0.f, 0.f, 0.f};
                acc = MFMA(xsf[tr][0], wf[et][0], acc);
                acc = MFMA(xsf[tr][1], wf[et][1], acc);
                const float bv = bm[et*16 + c];
                #pragma unroll
                for (int r = 0; r < 4; ++r)
                    hsv[tr][et][r] = fmaxf(acc[r] + bv, 0.f);
            }
        }
    };

    #pragma unroll 1
    for (int l = 0; l < NLAY; ++l) {
        // ---- hs1 -> strip -> A/B-frags
        gemmHs(W1p + l*DD*DD, b1p + l*DD);
        STAGE_STRIP(hsv);
        __syncthreads();
        s16x8 h1f[2][2];
        READ_AFRAG(h1f);
        asm volatile("" ::: "memory");   // h1f reads stay above hs2 strip writes

        // ---- hs2 -> strip (row-major, read by all waves in chunk loop)
        gemmHs(W2p + l*DD*DD, b2p + l*DD);
        STAGE_STRIP(hsv);

        // ---- hs3 -> LDS transposed [d][m], bf16
        gemmHs(W3p + l*DD*DD, b3p + l*DD);
        #pragma unroll
        for (int tr = 0; tr < 2; ++tr) {
            #pragma unroll
            for (int et = 0; et < 4; ++et) {
                s16x4 pk;
                #pragma unroll
                for (int r = 0; r < 4; ++r) pk[r] = f2bf(hsv[tr][et][r]);
                lds_write4(&hs3Ts[et*16 + c][n0 + tr*16 + g*4], pk);
            }
        }
        __syncthreads();   // hs2 strips + hs3T visible to all waves

        // ---- masked attention + PV, 8 chunks of 32 m-columns --------------
        // pv transposed: lane (g,c) tile (tr,dc): PV[n=n0+16tr+c][d=16dc+4g+r]
        f32x4 pv[2][4];
        {
            const f32x4 z4 = {0.f, 0.f, 0.f, 0.f};
            #pragma unroll
            for (int tr = 0; tr < 2; ++tr)
                #pragma unroll
                for (int dc = 0; dc < 4; ++dc) pv[tr][dc] = z4;
        }

        // working copies of the mask registers (rotated 16 bits per chunk)
        unsigned long long ma = mA, mb = mB;

        #pragma unroll 1
        for (int cc = 0; cc < 8; ++cc) {
            // hs2 chunk-row fragments (A-slot of S^T)
            s16x8 a2[2][2];
            #pragma unroll
            for (int mc = 0; mc < 2; ++mc)
                #pragma unroll
                for (int kb = 0; kb < 2; ++kb)
                    a2[mc][kb] = lds_read8(&hs2s[cc*32 + mc*16 + c][kb*32 + g*8]);

            // hs3^T fragments (A-slot of PV)
            s16x8 h3f[4];
            #pragma unroll
            for (int dc = 0; dc < 4; ++dc)
                h3f[dc] = lds_read8(&hs3Ts[dc*16 + c][cc*32 + g*8]);

            const unsigned mw = (unsigned)ma;   // low 16 bits = this chunk

            // S^T tiles: reg r of lane (g,c) = S^T[m=16mc+4g+r][n=16tr+c],
            // masked via register bit (bit-select == multiply by {0,1})
            float smv[2][2][4];
            #pragma unroll
            for (int tr = 0; tr < 2; ++tr) {
                #pragma unroll
                for (int mc = 0; mc < 2; ++mc) {
                    f32x4 st = {0.f, 0.f, 0.f, 0.f};
                    st = MFMA(a2[mc][0], h1f[tr][0], st);
                    st = MFMA(a2[mc][1], h1f[tr][1], st);
                    #pragma unroll
                    for (int r = 0; r < 4; ++r)
                        smv[tr][mc][r] =
                            ((mw >> ((tr*2 + mc)*4 + r)) & 1u) ? st[r] : 0.f;
                }
            }

            // build PV B-operand in registers + PV MFMAs (per-element, as R7)
            // elem j of lane (g,c) = S'^T[m=8g+j][n-col c]
            //   = reg (j&3), tile (g>>1), of lane (2*(g&1)+(j>>2))*16 + c
            #pragma unroll
            for (int tr = 0; tr < 2; ++tr) {
                s16x8 pb;
                #pragma unroll
                for (int j = 0; j < 8; ++j) {
                    const int srcl = ((2*(g & 1) + (j >> 2)) << 4) | c;
                    const float v0 = __shfl(smv[tr][0][j & 3], srcl);
                    const float v1 = __shfl(smv[tr][1][j & 3], srcl);
                    pb[j] = f2bf((g & 2) ? v1 : v0);
                }
                #pragma unroll
                for (int dc = 0; dc < 4; ++dc)
                    pv[tr][dc] = MFMA(h3f[dc], pb, pv[tr][dc]);
            }

            // rotate mask registers to the next chunk
            ma = (ma >> 16) | (mb << 48);
            mb >>= 16;
        }

        // ---- LayerNorm(pv) + residual (transposed layout) ------------------
        #pragma unroll
        for (int tr = 0; tr < 2; ++tr) {
            float s1 = 0.f, s2 = 0.f;
            #pragma unroll
            for (int dc = 0; dc < 4; ++dc)
                #pragma unroll
                for (int r = 0; r < 4; ++r) {
                    const float x = pv[tr][dc][r];
                    s1 += x; s2 += x*x;
                }
            s1 += __shfl_xor(s1, 16); s2 += __shfl_xor(s2, 16);
            s1 += __shfl_xor(s1, 32); s2 += __shfl_xor(s2, 32);
            const float mu  = s1 * 0.015625f;
            const float var = s2 * 0.015625f - mu*mu;
            const float rs  = rsqrtf(var + 1e-6f);
            #pragma unroll
            for (int dc = 0; dc < 4; ++dc) {
                const f32x4 lg = *(const f32x4*)&lngp[dc*16 + g*4];
                const f32x4 lb4 = *(const f32x4*)&lnbp[dc*16 + g*4];
                #pragma unroll
                for (int r = 0; r < 4; ++r)
                    xsC[tr][dc][r] += (pv[tr][dc][r] - mu) * rs * lg[r] + lb4[r];
            }
        }

        // ---- re-stage xs for next layer ------------------------------------
        if (l < NLAY - 1) {
            __syncthreads();          // all waves done reading hs2s/hs3Ts
            stageXS();
            __syncthreads();
            READ_AFRAG(xsf);
            asm volatile("" ::: "memory");
        }
    }

    // ---------------- final output: float4 per (tr,dc) ----------------------
    const size_t ob = (size_t)b * NN * DD;
    #pragma unroll
    for (int tr = 0; tr < 2; ++tr) {
        const int n = n0 + tr*16 + c;
        #pragma unroll
        for (int dc = 0; dc < 4; ++dc)
            *(f32x4*)&out[ob + (size_t)n*DD + dc*16 + g*4] = xsC[tr][dc];
    }
}

extern "C" void kernel_launch(void* const* d_in, const int* in_sizes, int n_in,
                              void* d_out, int out_size, void* d_ws, size_t ws_size,
                              hipStream_t stream) {
    const int*   fpr  = (const int*)  d_in[0];
    const float* adj  = (const float*)d_in[1];
    // d_in[2] = molecular_sizes — unused by the reference computation
    const float* wemb = (const float*)d_in[3];
    const float* pemb = (const float*)d_in[4];
    const float* eg   = (const float*)d_in[5];
    const float* eb   = (const float*)d_in[6];
    const float* W1   = (const float*)d_in[7];
    const float* b1   = (const float*)d_in[8];
    const float* W2   = (const float*)d_in[9];
    const float* b2   = (const float*)d_in[10];
    const float* W3   = (const float*)d_in[11];
    const float* b3   = (const float*)d_in[12];
    const float* lng  = (const float*)d_in[13];
    const float* lnb  = (const float*)d_in[14];

    mgnn_fused<<<dim3(NB), dim3(512), 0, stream>>>(
        fpr, adj, wemb, pemb, eg, eb, W1, b1, W2, b2, W3, b3, lng, lnb,
        (float*)d_out);
}